// Round 1
// baseline (507.939 us; speedup 1.0000x reference)
//
#include <hip/hip_runtime.h>
#include <hip/hip_bf16.h>
#include <cstdint>

#define NSHEET 16
#define MAXW 128
#define MAXH 128
#define MAXP 25
#define HIDDEN 1024
#define CNN_DIM 65536
#define IN_DIM 65611          // 65536 + 3*25
#define ACT_DIM 800
#define CHUNK 128
#define NCHUNK 513            // ceil(65611/128)
#define NVALID 800            // 16*25*2

// workspace byte offsets (all 256B aligned)
#define OFF_COMB 0            // float[65664]
#define OFF_SAT  262656       // u16[16][128][128]
#define OFF_P1   786944       // float[513][1024]
#define OFF_FITS 2888192      // int[800]
#define OFF_P2   2891520      // float[8][800]

// ---------------- K1: conv1+conv2 (blocks 0..15) and SAT (blocks 16..31) ----
__global__ __launch_bounds__(256) void k1_prep(
        const int* __restrict__ stocks, const int* __restrict__ psz,
        const int* __restrict__ pq,
        const float* __restrict__ c1w, const float* __restrict__ c1b,
        const float* __restrict__ c2w, const float* __restrict__ c2b,
        float* __restrict__ comb, unsigned short* __restrict__ satg)
{
    __shared__ __align__(16) unsigned char smem[49664];
    const int tid = threadIdx.x;
    if (blockIdx.x < NSHEET) {
        const int s = blockIdx.x;
        unsigned char* xs = smem;                      // [128][128] 0/1
        float* o1 = (float*)(smem + 16384);            // [2][64][64]
        float* wb = (float*)(smem + 16384 + 32768);    // 96 floats of weights
        const int* st = stocks + s * 16384;
        for (int k = 0; k < 64; ++k) {
            int idx = tid + k * 256;
            xs[idx] = (st[idx] == -1) ? 1 : 0;         // 1.0 where empty
        }
        if (tid < 96) {
            float v;
            if (tid < 18)      v = c1w[tid];
            else if (tid < 20) v = c1b[tid - 18];
            else if (tid < 92) v = c2w[tid - 20];
            else               v = c2b[tid - 92];
            wb[tid] = v;
        }
        __syncthreads();
        // conv1: 1->2 ch, 3x3, stride 2, pad 1 -> [2][64][64]
        for (int k = 0; k < 32; ++k) {
            int idx = tid + k * 256;
            int oc = idx >> 12;
            int r = idx & 4095;
            int oy = r >> 6, ox = r & 63;
            float acc = wb[18 + oc];
            #pragma unroll
            for (int ky = 0; ky < 3; ++ky) {
                int iy = 2 * oy - 1 + ky;
                if (iy < 0 || iy > 127) continue;
                #pragma unroll
                for (int kx = 0; kx < 3; ++kx) {
                    int ix = 2 * ox - 1 + kx;
                    if (ix < 0 || ix > 127) continue;
                    acc += (float)xs[iy * 128 + ix] * wb[oc * 9 + ky * 3 + kx];
                }
            }
            o1[idx] = fmaxf(acc, 0.f);
        }
        __syncthreads();
        // conv2: 2->4 ch, 3x3, stride 2, pad 1 -> [4][32][32] -> combined
        for (int k = 0; k < 16; ++k) {
            int idx = tid + k * 256;
            int oc = idx >> 10;
            int r = idx & 1023;
            int oy = r >> 5, ox = r & 31;
            float acc = wb[92 + oc];
            #pragma unroll
            for (int ic = 0; ic < 2; ++ic)
            #pragma unroll
            for (int ky = 0; ky < 3; ++ky) {
                int iy = 2 * oy - 1 + ky;
                if (iy < 0 || iy > 63) continue;
                #pragma unroll
                for (int kx = 0; kx < 3; ++kx) {
                    int ix = 2 * ox - 1 + kx;
                    if (ix < 0 || ix > 63) continue;
                    acc += o1[ic * 4096 + iy * 64 + ix] *
                           wb[20 + ((oc * 2 + ic) * 9 + ky * 3 + kx)];
                }
            }
            comb[s * 4096 + idx] = fmaxf(acc, 0.f);
        }
        // product features (one block writes them)
        if (s == 0 && tid < 3 * MAXP) {
            int p = tid / 3, r = tid - p * 3;
            comb[CNN_DIM + tid] = (float)(r < 2 ? psz[p * 2 + r] : pq[p]);
        }
    } else {
        // inclusive summed-area table per sheet, u16 (max 16384 fits)
        const int s = blockIdx.x - NSHEET;
        unsigned short* sat = (unsigned short*)smem;   // [128][132] padded
        const int* st = stocks + s * 16384;
        for (int k = 0; k < 64; ++k) {
            int idx = tid + k * 256;
            sat[(idx >> 7) * 132 + (idx & 127)] = (st[idx] != -1) ? 1 : 0;
        }
        __syncthreads();
        if (tid < 128) {                                // row prefix
            int run = 0;
            for (int c = 0; c < 128; ++c) {
                run += sat[tid * 132 + c];
                sat[tid * 132 + c] = (unsigned short)run;
            }
        }
        __syncthreads();
        if (tid < 128) {                                // col prefix
            int run = 0;
            for (int r = 0; r < 128; ++r) {
                run += sat[r * 132 + tid];
                sat[r * 132 + tid] = (unsigned short)run;
            }
        }
        __syncthreads();
        for (int k = 0; k < 64; ++k) {
            int idx = tid + k * 256;
            satg[s * 16384 + idx] = sat[(idx >> 7) * 132 + (idx & 127)];
        }
    }
}

// ---------------- K2: fc1 split-K partials (0..512) + valid scan (513..1312) -
__global__ __launch_bounds__(256) void k2_fc1_valid(
        const float* __restrict__ comb, const float* __restrict__ fc1w,
        const unsigned short* __restrict__ satg, const int* __restrict__ psz,
        float* __restrict__ part1, int* __restrict__ fits)
{
    const int tid = threadIdx.x;
    if (blockIdx.x < NCHUNK) {
        const int b = blockIdx.x;
        const int base = b * CHUNK;
        const int nr = min(CHUNK, IN_DIM - base);
        __shared__ float cl[CHUNK];
        float v = 0.f;
        if (tid < nr) v = comb[base + tid];
        if (tid < CHUNK) cl[tid] = v;
        // barrier + count of nonzero activations in this chunk
        int nz = __syncthreads_count(v != 0.f);
        float4 acc = {0.f, 0.f, 0.f, 0.f};
        if (nz != 0) {
            const float4* W4 = (const float4*)fc1w;
            #pragma unroll 4
            for (int i = 0; i < nr; ++i) {
                float cv = cl[i];               // broadcast, wave-uniform
                if (cv == 0.f) continue;        // skip 4KB row read
                float4 w = W4[(long)(base + i) * 256 + tid];
                acc.x += cv * w.x; acc.y += cv * w.y;
                acc.z += cv * w.z; acc.w += cv * w.w;
            }
        }
        ((float4*)part1)[b * 256 + tid] = acc;
    } else {
        const int vb = blockIdx.x - NCHUNK;
        const int s = vb / 50, pm = vb - s * 50;
        const int p = pm >> 1, m = pm & 1;
        const int w = psz[p * 2 + m];
        const int h = psz[p * 2 + 1 - m];
        const unsigned short* S = satg + s * 16384;
        const int imax = MAXW - w, jmax = MAXH - h;
        __shared__ int found;
        if (tid == 0) found = 0;
        __syncthreads();
        int f = 0;
        for (int pos = tid; pos < 16384; pos += 256) {
            int i = pos >> 7, j = pos & 127;
            if (i <= imax && j <= jmax) {
                int i2 = i + w - 1, j2 = j + h - 1;
                int sum = (int)S[i2 * 128 + j2]
                        - (i ? (int)S[(i - 1) * 128 + j2] : 0)
                        - (j ? (int)S[i2 * 128 + (j - 1)] : 0)
                        + ((i && j) ? (int)S[(i - 1) * 128 + (j - 1)] : 0);
                if (sum == 0) f = 1;            // empty window found
            }
        }
        if (f) atomicOr(&found, 1);
        __syncthreads();
        if (tid == 0) fits[s * 50 + pm] = found;
    }
}

// ---------------- K3: reduce h chunk (bias+relu) then fc2 partial ------------
__global__ __launch_bounds__(256) void k3_fc2part(
        const float* __restrict__ part1, const float* __restrict__ fc1b,
        const float* __restrict__ fc2w, float* __restrict__ part2)
{
    const int b = blockIdx.x;          // 0..7, k-chunk of 128 hidden units
    const int tid = threadIdx.x;
    const int j0 = b * 128;
    __shared__ float hl[128];
    if (tid < 128) {
        float s = fc1b[j0 + tid];
        #pragma unroll 4
        for (int c = 0; c < NCHUNK; ++c) s += part1[c * 1024 + j0 + tid];
        hl[tid] = fmaxf(s, 0.f);
    }
    __syncthreads();
    const int a4 = tid * 4;
    if (a4 < ACT_DIM) {                 // threads 0..199 active
        float4 acc = {0.f, 0.f, 0.f, 0.f};
        for (int k = 0; k < 128; ++k) {
            float hv = hl[k];
            if (hv == 0.f) continue;    // relu sparsity skip
            const float4 w = *(const float4*)(fc2w + (size_t)(j0 + k) * ACT_DIM + a4);
            acc.x += hv * w.x; acc.y += hv * w.y;
            acc.z += hv * w.z; acc.w += hv * w.w;
        }
        *(float4*)(part2 + b * ACT_DIM + a4) = acc;
    }
}

// ---------------- K4: reduce logits, mask, softmax ---------------------------
__global__ __launch_bounds__(256) void k4_final(
        const float* __restrict__ part2, const float* __restrict__ fc2b,
        const int* __restrict__ fits, const int* __restrict__ pq,
        float* __restrict__ out)
{
    const int tid = threadIdx.x;
    __shared__ float lg[ACT_DIM];
    __shared__ float red[8];
    __shared__ float gval[2];
    for (int a = tid; a < ACT_DIM; a += 256) {
        float v = fc2b[a];
        #pragma unroll
        for (int c = 0; c < 8; ++c) v += part2[c * ACT_DIM + a];
        int m = a & 1, t2 = a >> 1;
        int p = t2 % 25, s = t2 / 25;
        int v0 = fits[s * 50 + p * 2];
        int v1 = fits[s * 50 + p * 2 + 1];
        bool valid = (m == 0 ? (v0 != 0) : (v1 != 0 && v0 == 0)) && (pq[p] > 0);
        lg[a] = valid ? v : -1e9f;
    }
    __syncthreads();
    float lm = -3e38f;
    for (int a = tid; a < ACT_DIM; a += 256) lm = fmaxf(lm, lg[a]);
    for (int off = 32; off >= 1; off >>= 1) lm = fmaxf(lm, __shfl_down(lm, off));
    if ((tid & 63) == 0) red[tid >> 6] = lm;
    __syncthreads();
    if (tid == 0) {
        float m = red[0];
        for (int w = 1; w < 4; ++w) m = fmaxf(m, red[w]);
        gval[0] = m;
    }
    __syncthreads();
    const float gmax = gval[0];
    float ls = 0.f;
    for (int a = tid; a < ACT_DIM; a += 256) {
        float e = expf(lg[a] - gmax);   // -1e9 underflows to 0 like reference
        lg[a] = e;
        ls += e;
    }
    for (int off = 32; off >= 1; off >>= 1) ls += __shfl_down(ls, off);
    if ((tid & 63) == 0) red[tid >> 6] = ls;
    __syncthreads();
    if (tid == 0) gval[1] = red[0] + red[1] + red[2] + red[3];
    __syncthreads();
    const float inv = 1.f / gval[1];
    for (int a = tid; a < ACT_DIM; a += 256) out[a] = lg[a] * inv;
}

extern "C" void kernel_launch(void* const* d_in, const int* in_sizes, int n_in,
                              void* d_out, int out_size, void* d_ws, size_t ws_size,
                              hipStream_t stream) {
    const int*   stocks = (const int*)d_in[0];
    const int*   psz    = (const int*)d_in[1];
    const int*   pq     = (const int*)d_in[2];
    const float* c1w    = (const float*)d_in[3];
    const float* c1b    = (const float*)d_in[4];
    const float* c2w    = (const float*)d_in[5];
    const float* c2b    = (const float*)d_in[6];
    const float* fc1w   = (const float*)d_in[7];
    const float* fc1b   = (const float*)d_in[8];
    const float* fc2w   = (const float*)d_in[9];
    const float* fc2b   = (const float*)d_in[10];
    float* out = (float*)d_out;
    char*  ws  = (char*)d_ws;

    float*          comb  = (float*)(ws + OFF_COMB);
    unsigned short* satg  = (unsigned short*)(ws + OFF_SAT);
    float*          part1 = (float*)(ws + OFF_P1);
    int*            fitsp = (int*)(ws + OFF_FITS);
    float*          part2 = (float*)(ws + OFF_P2);

    hipLaunchKernelGGL(k1_prep, dim3(2 * NSHEET), dim3(256), 0, stream,
                       stocks, psz, pq, c1w, c1b, c2w, c2b, comb, satg);
    hipLaunchKernelGGL(k2_fc1_valid, dim3(NCHUNK + NVALID), dim3(256), 0, stream,
                       comb, fc1w, satg, psz, part1, fitsp);
    hipLaunchKernelGGL(k3_fc2part, dim3(8), dim3(256), 0, stream,
                       part1, fc1b, fc2w, part2);
    hipLaunchKernelGGL(k4_final, dim3(1), dim3(256), 0, stream,
                       part2, fc2b, fitsp, pq, out);
}

// Round 2
// 404.465 us; speedup vs baseline: 1.2558x; 1.2558x over previous
//
#include <hip/hip_runtime.h>
#include <hip/hip_bf16.h>
#include <cstdint>

#define NSHEET 16
#define MAXW 128
#define MAXH 128
#define MAXP 25
#define HIDDEN 1024
#define CNN_DIM 65536
#define IN_DIM 65611          // 65536 + 3*25
#define ACT_DIM 800
#define CHUNK 128
#define NCHUNK 513            // ceil(65611/128)
#define NVALID 800            // 16*25*2
#define FC2_BLOCKS 32         // split-K blocks for fc2 (32 k's each)

// workspace byte offsets (all 256B aligned)
#define OFF_COMB 0            // float[65664]
#define OFF_SAT  262656       // u16[16][128][128]
#define OFF_P1   786944       // float[513][1024]
#define OFF_H    2888192      // float[1024]
#define OFF_FITS 2892288      // int[800]
#define OFF_P2   2895488      // float[32][800]

// ---------------- K1: conv1+conv2 (blocks 0..15) and SAT (blocks 16..31) ----
__global__ __launch_bounds__(256) void k1_prep(
        const int* __restrict__ stocks, const int* __restrict__ psz,
        const int* __restrict__ pq,
        const float* __restrict__ c1w, const float* __restrict__ c1b,
        const float* __restrict__ c2w, const float* __restrict__ c2b,
        float* __restrict__ comb, unsigned short* __restrict__ satg)
{
    __shared__ __align__(16) unsigned char smem[49664];
    const int tid = threadIdx.x;
    if (blockIdx.x < NSHEET) {
        const int s = blockIdx.x;
        unsigned char* xs = smem;                      // [128][128] 0/1
        float* o1 = (float*)(smem + 16384);            // [2][64][64]
        float* wb = (float*)(smem + 16384 + 32768);    // 96 floats of weights
        const int* st = stocks + s * 16384;
        for (int k = 0; k < 64; ++k) {
            int idx = tid + k * 256;
            xs[idx] = (st[idx] == -1) ? 1 : 0;         // 1.0 where empty
        }
        if (tid < 96) {
            float v;
            if (tid < 18)      v = c1w[tid];
            else if (tid < 20) v = c1b[tid - 18];
            else if (tid < 92) v = c2w[tid - 20];
            else               v = c2b[tid - 92];
            wb[tid] = v;
        }
        __syncthreads();
        // conv1: 1->2 ch, 3x3, stride 2, pad 1 -> [2][64][64]
        for (int k = 0; k < 32; ++k) {
            int idx = tid + k * 256;
            int oc = idx >> 12;
            int r = idx & 4095;
            int oy = r >> 6, ox = r & 63;
            float acc = wb[18 + oc];
            #pragma unroll
            for (int ky = 0; ky < 3; ++ky) {
                int iy = 2 * oy - 1 + ky;
                if (iy < 0 || iy > 127) continue;
                #pragma unroll
                for (int kx = 0; kx < 3; ++kx) {
                    int ix = 2 * ox - 1 + kx;
                    if (ix < 0 || ix > 127) continue;
                    acc += (float)xs[iy * 128 + ix] * wb[oc * 9 + ky * 3 + kx];
                }
            }
            o1[idx] = fmaxf(acc, 0.f);
        }
        __syncthreads();
        // conv2: 2->4 ch, 3x3, stride 2, pad 1 -> [4][32][32] -> combined
        for (int k = 0; k < 16; ++k) {
            int idx = tid + k * 256;
            int oc = idx >> 10;
            int r = idx & 1023;
            int oy = r >> 5, ox = r & 31;
            float acc = wb[92 + oc];
            #pragma unroll
            for (int ic = 0; ic < 2; ++ic)
            #pragma unroll
            for (int ky = 0; ky < 3; ++ky) {
                int iy = 2 * oy - 1 + ky;
                if (iy < 0 || iy > 63) continue;
                #pragma unroll
                for (int kx = 0; kx < 3; ++kx) {
                    int ix = 2 * ox - 1 + kx;
                    if (ix < 0 || ix > 63) continue;
                    acc += o1[ic * 4096 + iy * 64 + ix] *
                           wb[20 + ((oc * 2 + ic) * 9 + ky * 3 + kx)];
                }
            }
            comb[s * 4096 + idx] = fmaxf(acc, 0.f);
        }
        // product features (one block writes them)
        if (s == 0 && tid < 3 * MAXP) {
            int p = tid / 3, r = tid - p * 3;
            comb[CNN_DIM + tid] = (float)(r < 2 ? psz[p * 2 + r] : pq[p]);
        }
    } else {
        // inclusive summed-area table per sheet, u16 (max 16384 fits)
        const int s = blockIdx.x - NSHEET;
        unsigned short* sat = (unsigned short*)smem;   // [128][132] padded
        const int* st = stocks + s * 16384;
        for (int k = 0; k < 64; ++k) {
            int idx = tid + k * 256;
            sat[(idx >> 7) * 132 + (idx & 127)] = (st[idx] != -1) ? 1 : 0;
        }
        __syncthreads();
        if (tid < 128) {                                // row prefix
            int run = 0;
            for (int c = 0; c < 128; ++c) {
                run += sat[tid * 132 + c];
                sat[tid * 132 + c] = (unsigned short)run;
            }
        }
        __syncthreads();
        if (tid < 128) {                                // col prefix
            int run = 0;
            for (int r = 0; r < 128; ++r) {
                run += sat[r * 132 + tid];
                sat[r * 132 + tid] = (unsigned short)run;
            }
        }
        __syncthreads();
        for (int k = 0; k < 64; ++k) {
            int idx = tid + k * 256;
            satg[s * 16384 + idx] = sat[(idx >> 7) * 132 + (idx & 127)];
        }
    }
}

// ---------------- K2: fc1 split-K partials (0..512) + valid scan (513..1312) -
__global__ __launch_bounds__(256) void k2_fc1_valid(
        const float* __restrict__ comb, const float* __restrict__ fc1w,
        const unsigned short* __restrict__ satg, const int* __restrict__ psz,
        float* __restrict__ part1, int* __restrict__ fits)
{
    const int tid = threadIdx.x;
    if (blockIdx.x < NCHUNK) {
        const int b = blockIdx.x;
        const int base = b * CHUNK;
        const int nr = min(CHUNK, IN_DIM - base);
        // order-preserving compaction of nonzero activations (ballot+popc)
        __shared__ float cval[CHUNK];
        __shared__ int   cidx[CHUNK];
        __shared__ int   wcnt[2];
        float v = 0.f; bool nz = false; int pre = 0;
        if (tid < CHUNK) {                 // waves 0,1 (wave-aligned branch)
            if (tid < nr) v = comb[base + tid];
            nz = (v != 0.f);
            unsigned long long m = __ballot(nz);
            int lane = tid & 63;
            pre = __popcll(m & ((1ull << lane) - 1ull));
            if (lane == 0) wcnt[tid >> 6] = __popcll(m);
        }
        __syncthreads();
        const int w0c = wcnt[0];
        const int total = w0c + wcnt[1];
        if (nz) {
            int pos = ((tid >> 6) ? w0c : 0) + pre;
            cval[pos] = v;
            cidx[pos] = base + tid;
        }
        __syncthreads();
        // branch-free, 4-deep pipelined row accumulate
        float4 acc = {0.f, 0.f, 0.f, 0.f};
        const float4* W4 = (const float4*)fc1w;
        int i = 0;
        for (; i + 4 <= total; i += 4) {
            int r0 = cidx[i], r1 = cidx[i + 1], r2 = cidx[i + 2], r3 = cidx[i + 3];
            float4 a0 = W4[r0 * 256 + tid];
            float4 a1 = W4[r1 * 256 + tid];
            float4 a2 = W4[r2 * 256 + tid];
            float4 a3 = W4[r3 * 256 + tid];
            float c0 = cval[i], c1 = cval[i + 1], c2 = cval[i + 2], c3 = cval[i + 3];
            acc.x += c0 * a0.x; acc.y += c0 * a0.y; acc.z += c0 * a0.z; acc.w += c0 * a0.w;
            acc.x += c1 * a1.x; acc.y += c1 * a1.y; acc.z += c1 * a1.z; acc.w += c1 * a1.w;
            acc.x += c2 * a2.x; acc.y += c2 * a2.y; acc.z += c2 * a2.z; acc.w += c2 * a2.w;
            acc.x += c3 * a3.x; acc.y += c3 * a3.y; acc.z += c3 * a3.z; acc.w += c3 * a3.w;
        }
        for (; i < total; ++i) {
            float cv = cval[i];
            float4 w = W4[cidx[i] * 256 + tid];
            acc.x += cv * w.x; acc.y += cv * w.y;
            acc.z += cv * w.z; acc.w += cv * w.w;
        }
        ((float4*)part1)[b * 256 + tid] = acc;
    } else {
        const int vb = blockIdx.x - NCHUNK;
        const int s = vb / 50, pm = vb - s * 50;
        const int p = pm >> 1, m = pm & 1;
        const int w = psz[p * 2 + m];
        const int h = psz[p * 2 + 1 - m];
        const unsigned short* S = satg + s * 16384;
        const int imax = MAXW - w, jmax = MAXH - h;
        __shared__ int found;
        if (tid == 0) found = 0;
        __syncthreads();
        int f = 0;
        for (int pos = tid; pos < 16384; pos += 256) {
            int i = pos >> 7, j = pos & 127;
            if (i <= imax && j <= jmax) {
                int i2 = i + w - 1, j2 = j + h - 1;
                int sum = (int)S[i2 * 128 + j2]
                        - (i ? (int)S[(i - 1) * 128 + j2] : 0)
                        - (j ? (int)S[i2 * 128 + (j - 1)] : 0)
                        + ((i && j) ? (int)S[(i - 1) * 128 + (j - 1)] : 0);
                if (sum == 0) f = 1;            // empty window found
            }
        }
        if (f) atomicOr(&found, 1);
        __syncthreads();
        if (tid == 0) fits[s * 50 + pm] = found;
    }
}

// ---------------- K3a: reduce part1 -> h (bias + relu) ----------------------
__global__ __launch_bounds__(256) void k3a_hred(
        const float* __restrict__ part1, const float* __restrict__ fc1b,
        float* __restrict__ h)
{
    const int j0 = blockIdx.x * 16;              // 64 blocks x 16 hidden units
    const int lane16 = threadIdx.x & 15;
    const int r = threadIdx.x >> 4;              // 16 chunk-groups
    float s = 0.f;
    for (int c = r; c < NCHUNK; c += 16)
        s += part1[c * 1024 + j0 + lane16];
    __shared__ float red[16][17];
    red[r][lane16] = s;
    __syncthreads();
    if (threadIdx.x < 16) {
        float t = fc1b[j0 + threadIdx.x];
        #pragma unroll
        for (int k = 0; k < 16; ++k) t += red[k][threadIdx.x];
        h[j0 + threadIdx.x] = fmaxf(t, 0.f);
    }
}

// ---------------- K3b: fc2 split-K partials ---------------------------------
__global__ __launch_bounds__(256) void k3b_fc2part(
        const float* __restrict__ h, const float* __restrict__ fc2w,
        float* __restrict__ part2)
{
    const int b = blockIdx.x;          // 0..31, k-chunk of 32 hidden units
    const int tid = threadIdx.x;
    const int k0 = b * 32;
    __shared__ float hl[32];
    if (tid < 32) hl[tid] = h[k0 + tid];
    __syncthreads();
    const int a4 = tid * 4;
    if (a4 < ACT_DIM) {                 // threads 0..199 active
        float4 acc = {0.f, 0.f, 0.f, 0.f};
        #pragma unroll 4
        for (int k = 0; k < 32; ++k) {
            float hv = hl[k];
            if (hv == 0.f) continue;    // relu sparsity skip (wave-uniform)
            const float4 w = *(const float4*)(fc2w + (size_t)(k0 + k) * ACT_DIM + a4);
            acc.x += hv * w.x; acc.y += hv * w.y;
            acc.z += hv * w.z; acc.w += hv * w.w;
        }
        *(float4*)(part2 + b * ACT_DIM + a4) = acc;
    }
}

// ---------------- K4: reduce logits, mask, softmax ---------------------------
__global__ __launch_bounds__(256) void k4_final(
        const float* __restrict__ part2, const float* __restrict__ fc2b,
        const int* __restrict__ fits, const int* __restrict__ pq,
        float* __restrict__ out)
{
    const int tid = threadIdx.x;
    __shared__ float lg[ACT_DIM];
    __shared__ float red[8];
    __shared__ float gval[2];
    for (int a = tid; a < ACT_DIM; a += 256) {
        float v = fc2b[a];
        #pragma unroll
        for (int c = 0; c < FC2_BLOCKS; ++c) v += part2[c * ACT_DIM + a];
        int m = a & 1, t2 = a >> 1;
        int p = t2 % 25, s = t2 / 25;
        int v0 = fits[s * 50 + p * 2];
        int v1 = fits[s * 50 + p * 2 + 1];
        bool valid = (m == 0 ? (v0 != 0) : (v1 != 0 && v0 == 0)) && (pq[p] > 0);
        lg[a] = valid ? v : -1e9f;
    }
    __syncthreads();
    float lm = -3e38f;
    for (int a = tid; a < ACT_DIM; a += 256) lm = fmaxf(lm, lg[a]);
    for (int off = 32; off >= 1; off >>= 1) lm = fmaxf(lm, __shfl_down(lm, off));
    if ((tid & 63) == 0) red[tid >> 6] = lm;
    __syncthreads();
    if (tid == 0) {
        float m = red[0];
        for (int w = 1; w < 4; ++w) m = fmaxf(m, red[w]);
        gval[0] = m;
    }
    __syncthreads();
    const float gmax = gval[0];
    float ls = 0.f;
    for (int a = tid; a < ACT_DIM; a += 256) {
        float e = expf(lg[a] - gmax);   // -1e9 underflows to 0 like reference
        lg[a] = e;
        ls += e;
    }
    for (int off = 32; off >= 1; off >>= 1) ls += __shfl_down(ls, off);
    if ((tid & 63) == 0) red[tid >> 6] = ls;
    __syncthreads();
    if (tid == 0) gval[1] = red[0] + red[1] + red[2] + red[3];
    __syncthreads();
    const float inv = 1.f / gval[1];
    for (int a = tid; a < ACT_DIM; a += 256) out[a] = lg[a] * inv;
}

extern "C" void kernel_launch(void* const* d_in, const int* in_sizes, int n_in,
                              void* d_out, int out_size, void* d_ws, size_t ws_size,
                              hipStream_t stream) {
    const int*   stocks = (const int*)d_in[0];
    const int*   psz    = (const int*)d_in[1];
    const int*   pq     = (const int*)d_in[2];
    const float* c1w    = (const float*)d_in[3];
    const float* c1b    = (const float*)d_in[4];
    const float* c2w    = (const float*)d_in[5];
    const float* c2b    = (const float*)d_in[6];
    const float* fc1w   = (const float*)d_in[7];
    const float* fc1b   = (const float*)d_in[8];
    const float* fc2w   = (const float*)d_in[9];
    const float* fc2b   = (const float*)d_in[10];
    float* out = (float*)d_out;
    char*  ws  = (char*)d_ws;

    float*          comb  = (float*)(ws + OFF_COMB);
    unsigned short* satg  = (unsigned short*)(ws + OFF_SAT);
    float*          part1 = (float*)(ws + OFF_P1);
    float*          hbuf  = (float*)(ws + OFF_H);
    int*            fitsp = (int*)(ws + OFF_FITS);
    float*          part2 = (float*)(ws + OFF_P2);

    hipLaunchKernelGGL(k1_prep, dim3(2 * NSHEET), dim3(256), 0, stream,
                       stocks, psz, pq, c1w, c1b, c2w, c2b, comb, satg);
    hipLaunchKernelGGL(k2_fc1_valid, dim3(NCHUNK + NVALID), dim3(256), 0, stream,
                       comb, fc1w, satg, psz, part1, fitsp);
    hipLaunchKernelGGL(k3a_hred, dim3(64), dim3(256), 0, stream,
                       part1, fc1b, hbuf);
    hipLaunchKernelGGL(k3b_fc2part, dim3(FC2_BLOCKS), dim3(256), 0, stream,
                       hbuf, fc2w, part2);
    hipLaunchKernelGGL(k4_final, dim3(1), dim3(256), 0, stream,
                       part2, fc2b, fitsp, pq, out);
}